// Round 2
// baseline (14291.968 us; speedup 1.0000x reference)
//
#include <hip/hip_runtime.h>
#include <hip/hip_bf16.h>
#include <math.h>

// Problem constants
#define B   32
#define T   64
#define E   512
#define H   1024
#define V   32000
#define G3  3072            // 3*H
#define TV  (T*V)           // 2048000
#define BTV ((size_t)B*T*V) // 65536000
#define SOS 1
#define NVB 250             // tier-B logits v-blocks of 128
#define NPC 1000            // tier-A partial columns (250 blocks * 4 waves)

// ---------------- tier-B (fallback) ws layout (float offsets) ----------------
#define WS_H0   0          // 2 * B*H (ping-pong)
#define WS_H1   65536      // 2 * B*H
#define WS_GI0  131072     // B*3H
#define WS_GH0  229376
#define WS_GI1  327680
#define WS_GH1  425984
#define WS_PM   524288     // B*NVB
#define WS_PS   532288
#define WS_PI   540288     // ints
#define WS_TOK  548288     // (T+1)*B ints

// ---------------- tier-A ws layout ----------------
// bytes [0, 65536000)              : Whi  (V*H bf16)
// bytes [65536000, 131072000)      : Wlo  (V*H bf16)
// float region starts at float offset 32768000:
#define AF_BASE 32768000
#define AH0     0          // 2*B*H f32 ping-pong
#define AH1     65536
#define AGI0    131072     // B*3H f32
#define AGH0    229376
#define AGI1    327680
#define AGH1    425984
#define AH1HI   524288     // B*H bf16 = 16384 f32 slots
#define AH1LO   540672
#define APM     557056     // B*NPC f32
#define APS     589056
#define API     621056     // B*NPC ints
#define ATOK    653056     // (T+1)*B ints
#define ALSE    655136     // T*B f32
#define ACNT    657184     // T ints
#define AF_END  657248
#define NEED_A  (((size_t)AF_BASE + AF_END) * 4)   // 133,700,992 bytes

typedef __bf16 bf8   __attribute__((ext_vector_type(8)));
typedef __bf16 bf4v  __attribute__((ext_vector_type(4)));
typedef float  f32x4 __attribute__((ext_vector_type(4)));

__device__ inline f32x4 mfma16(bf8 a, bf8 b, f32x4 c) {
    return __builtin_amdgcn_mfma_f32_16x16x32_bf16(a, b, c, 0, 0, 0);
}

__global__ __launch_bounds__(256) void init_kernel(
    const float* __restrict__ ehid, float* __restrict__ h0,
    float* __restrict__ h1, int* __restrict__ tok0, int* __restrict__ cnt)
{
    int idx = blockIdx.x * 256 + threadIdx.x;   // 0..65535
    if (idx < B * H) h0[idx] = ehid[idx];
    else             h1[idx - B * H] = ehid[idx];
    if (idx < B) tok0[idx] = SOS;
    if (cnt && idx < T) cnt[idx] = 0;
}

// split w_out f32 -> hi/lo bf16 (tier A, once per launch)
__global__ __launch_bounds__(256) void splitw_kernel(
    const float* __restrict__ w, __bf16* __restrict__ hi, __bf16* __restrict__ lo)
{
    const size_t n4 = (size_t)V * H / 4;
    size_t i = (size_t)blockIdx.x * 256 + threadIdx.x;
    const size_t stride = (size_t)gridDim.x * 256;
    for (; i < n4; i += stride) {
        float4 v = *(const float4*)(w + i * 4);
        float a[4] = {v.x, v.y, v.z, v.w};
        bf4v hv, lv;
        #pragma unroll
        for (int j = 0; j < 4; ++j) {
            __bf16 h = (__bf16)a[j];
            hv[j] = h;
            lv[j] = (__bf16)(a[j] - (float)h);
        }
        *(bf4v*)(hi + i * 4) = hv;
        *(bf4v*)(lo + i * 4) = lv;
    }
}

// G = A @ W^T for a [B, 3H] gate pre-activation. blocks 0..95 -> Gi, 96..191 -> Gh.
// For layer 0's Gi, A==nullptr means gather rows from embedding via tok.
__global__ __launch_bounds__(256) void gates_kernel(
    const float* __restrict__ Agi, const float* __restrict__ emb,
    const int* __restrict__ tok, const float* __restrict__ Agh,
    const float* __restrict__ Wih, int Kgi, const float* __restrict__ Whh,
    float* __restrict__ Gi, float* __restrict__ Gh)
{
    const int tid = threadIdx.x;
    const bool isGh = blockIdx.x >= 96;
    const int ntile = isGh ? (blockIdx.x - 96) : blockIdx.x;
    const float* W = isGh ? Whh : Wih;
    const float* A = isGh ? Agh : Agi;
    float* G = isGh ? Gh : Gi;
    const int K = isGh ? H : Kgi;
    const bool gather = (!isGh) && (A == nullptr);

    __shared__ float4 As4[B][17];     // 32 x 64 floats (+1 f4 pad)
    __shared__ float4 Ws4[32][17];
    __shared__ int stok[B];
    if (gather && tid < B) stok[tid] = tok[tid];
    __syncthreads();

    const int tx = tid & 15, ty = tid >> 4;
    const int b0 = 2 * tx, n0 = 2 * ty;
    float acc00 = 0.f, acc01 = 0.f, acc10 = 0.f, acc11 = 0.f;

    for (int kc = 0; kc < K; kc += 64) {
        for (int u = tid; u < 32 * 16; u += 256) {
            int row = u >> 4, c = u & 15;
            const float* src = gather ? (emb + (size_t)stok[row] * E)
                                      : (A + (size_t)row * K);
            As4[row][c] = *(const float4*)(src + kc + c * 4);
        }
        for (int u = tid; u < 32 * 16; u += 256) {
            int row = u >> 4, c = u & 15;
            Ws4[row][c] = *(const float4*)(W + (size_t)(ntile * 32 + row) * K + kc + c * 4);
        }
        __syncthreads();
        #pragma unroll
        for (int kq = 0; kq < 16; ++kq) {
            float4 a0 = As4[b0][kq], a1 = As4[b0 + 1][kq];
            float4 w0 = Ws4[n0][kq], w1 = Ws4[n0 + 1][kq];
            acc00 += a0.x*w0.x + a0.y*w0.y + a0.z*w0.z + a0.w*w0.w;
            acc01 += a0.x*w1.x + a0.y*w1.y + a0.z*w1.z + a0.w*w1.w;
            acc10 += a1.x*w0.x + a1.y*w0.y + a1.z*w0.z + a1.w*w0.w;
            acc11 += a1.x*w1.x + a1.y*w1.y + a1.z*w1.z + a1.w*w1.w;
        }
        __syncthreads();
    }
    const int ng = ntile * 32 + n0;
    G[(size_t)(b0    ) * G3 + ng    ] = acc00;
    G[(size_t)(b0    ) * G3 + ng + 1] = acc01;
    G[(size_t)(b0 + 1) * G3 + ng    ] = acc10;
    G[(size_t)(b0 + 1) * G3 + ng + 1] = acc11;
}

// PyTorch GRU cell combine: gates (r,z,n) at cols j, j+H, j+2H.
__global__ __launch_bounds__(256) void gru_combine(
    const float* __restrict__ Gi, const float* __restrict__ Gh,
    const float* __restrict__ bih, const float* __restrict__ bhh,
    const float* __restrict__ hold, float* __restrict__ hnew,
    float* __restrict__ fin, __bf16* __restrict__ hhi, __bf16* __restrict__ hlo)
{
    int idx = blockIdx.x * 256 + threadIdx.x;   // 0..32767
    int b = idx >> 10, j = idx & 1023;
    size_t g = (size_t)b * G3 + j;
    float ir = Gi[g]         + bih[j];
    float hr = Gh[g]         + bhh[j];
    float iz = Gi[g + H]     + bih[j + H];
    float hz = Gh[g + H]     + bhh[j + H];
    float in_ = Gi[g + 2*H]  + bih[j + 2*H];
    float hn  = Gh[g + 2*H]  + bhh[j + 2*H];
    float r = 1.f / (1.f + expf(-(ir + hr)));
    float z = 1.f / (1.f + expf(-(iz + hz)));
    float n = tanhf(in_ + r * hn);
    float hv = (1.f - z) * n + z * hold[idx];
    hnew[idx] = hv;
    if (hhi) {
        __bf16 h = (__bf16)hv;
        hhi[idx] = h;
        hlo[idx] = (__bf16)(hv - (float)h);
    }
    if (fin) fin[idx] = hv;
}

// per-(m-tile,reg) row reduce over 32 v within the quarter's 16 lanes
__device__ inline void row_partial(float v0, float v1, int vbase, int r, int row,
    int pcol, float* __restrict__ pm, float* __restrict__ ps, int* __restrict__ pidx)
{
    float mx; int ix;
    if (v1 > v0) { mx = v1; ix = vbase + 16 + r; }
    else         { mx = v0; ix = vbase + r; }
    #pragma unroll
    for (int mask = 8; mask; mask >>= 1) {
        float om = __shfl_xor(mx, mask, 16);
        int   oi = __shfl_xor(ix, mask, 16);
        if (om > mx || (om == mx && oi < ix)) { mx = om; ix = oi; }
    }
    float s = expf(v0 - mx) + expf(v1 - mx);
    #pragma unroll
    for (int mask = 8; mask; mask >>= 1) s += __shfl_xor(s, mask, 16);
    if (r == 0) {
        pm[(size_t)row * NPC + pcol] = mx;
        ps[(size_t)row * NPC + pcol] = s;
        pidx[(size_t)row * NPC + pcol] = ix;
    }
}

// tier-A logits: 3-term split-bf16 MFMA, 250 blocks x 4 waves, 128 v/block.
// Last block (atomic counter) merges partials -> next token + LSE.
__global__ __launch_bounds__(256) void logits_mfma_kernel(
    const __bf16* __restrict__ Ahi, const __bf16* __restrict__ Alo,
    const __bf16* __restrict__ Whi, const __bf16* __restrict__ Wlo,
    const float* __restrict__ bout, float* __restrict__ out, int t,
    float* __restrict__ pm, float* __restrict__ ps, int* __restrict__ pidx,
    int* __restrict__ tok_next, float* __restrict__ lse_out, int* __restrict__ cnt)
{
    const int tid = threadIdx.x;
    const int wave = tid >> 6, lane = tid & 63;
    const int q = lane >> 4, r = lane & 15;
    const int blk = blockIdx.x;
    const int vbase = blk * 128 + wave * 32;

    const __bf16* a0h = Ahi + (size_t)r * H + q * 8;
    const __bf16* a1h = a0h + 16 * H;
    const __bf16* a0l = Alo + (size_t)r * H + q * 8;
    const __bf16* a1l = a0l + 16 * H;
    const __bf16* w0h = Whi + (size_t)(vbase + r) * H + q * 8;
    const __bf16* w1h = w0h + 16 * H;
    const __bf16* w0l = Wlo + (size_t)(vbase + r) * H + q * 8;
    const __bf16* w1l = w0l + 16 * H;

    f32x4 acc00 = {0.f,0.f,0.f,0.f}, acc01 = {0.f,0.f,0.f,0.f};
    f32x4 acc10 = {0.f,0.f,0.f,0.f}, acc11 = {0.f,0.f,0.f,0.f};

    #pragma unroll 4
    for (int ko = 0; ko < H; ko += 32) {
        bf8 A0h = *(const bf8*)(a0h + ko);
        bf8 A1h = *(const bf8*)(a1h + ko);
        bf8 A0l = *(const bf8*)(a0l + ko);
        bf8 A1l = *(const bf8*)(a1l + ko);
        bf8 W0h = *(const bf8*)(w0h + ko);
        bf8 W1h = *(const bf8*)(w1h + ko);
        bf8 W0l = *(const bf8*)(w0l + ko);
        bf8 W1l = *(const bf8*)(w1l + ko);
        acc00 = mfma16(A0h, W0h, acc00);
        acc00 = mfma16(A0h, W0l, acc00);
        acc00 = mfma16(A0l, W0h, acc00);
        acc01 = mfma16(A0h, W1h, acc01);
        acc01 = mfma16(A0h, W1l, acc01);
        acc01 = mfma16(A0l, W1h, acc01);
        acc10 = mfma16(A1h, W0h, acc10);
        acc10 = mfma16(A1h, W0l, acc10);
        acc10 = mfma16(A1l, W0h, acc10);
        acc11 = mfma16(A1h, W1h, acc11);
        acc11 = mfma16(A1h, W1l, acc11);
        acc11 = mfma16(A1l, W1h, acc11);
    }

    // epilogue: bias, store raw logits, per-wave partials
    const float bb0 = bout[vbase + r];
    const float bb1 = bout[vbase + 16 + r];
    const int pcol = blk * 4 + wave;
    const size_t obase = (size_t)t * V + vbase + r;

    #pragma unroll
    for (int reg = 0; reg < 4; ++reg) {
        int row0 = q * 4 + reg;
        float v00 = acc00[reg] + bb0, v01 = acc01[reg] + bb1;
        out[(size_t)row0 * TV + obase]      = v00;
        out[(size_t)row0 * TV + obase + 16] = v01;
        row_partial(v00, v01, vbase, r, row0, pcol, pm, ps, pidx);
        int row1 = 16 + q * 4 + reg;
        float v10 = acc10[reg] + bb0, v11 = acc11[reg] + bb1;
        out[(size_t)row1 * TV + obase]      = v10;
        out[(size_t)row1 * TV + obase + 16] = v11;
        row_partial(v10, v11, vbase, r, row1, pcol, pm, ps, pidx);
    }

    // last block merges all partials
    __shared__ int lastFlag;
    __syncthreads();                 // drain this block's stores
    if (tid == 0) {
        __threadfence();             // release (L2 writeback, device scope)
        int old = atomicAdd(cnt + t, 1);
        lastFlag = (old == (int)gridDim.x - 1);
    }
    __syncthreads();
    if (lastFlag) {
        __threadfence();             // acquire
        const int row = tid >> 3, part = tid & 7;
        const float* pmr = pm + (size_t)row * NPC;
        const float* psr = ps + (size_t)row * NPC;
        const int*   pir = pidx + (size_t)row * NPC;
        float M = -INFINITY, S = 0.f; int Ix = 0x7fffffff;
        for (int j = 0; j < NPC / 8; ++j) {
            int c = part * (NPC / 8) + j;
            float m = pmr[c], s = psr[c]; int ix = pir[c];
            if (m > M) { S = S * expf(M - m) + s; M = m; Ix = ix; }
            else { S += s * expf(m - M); if (m == M && ix < Ix) Ix = ix; }
        }
        #pragma unroll
        for (int mask = 4; mask; mask >>= 1) {
            float om = __shfl_xor(M, mask, 8);
            float oS = __shfl_xor(S, mask, 8);
            int   oI = __shfl_xor(Ix, mask, 8);
            if (om > M) { S = S * expf(M - om) + oS; M = om; Ix = oI; }
            else { S += oS * expf(om - M); if (om == M && oI < Ix) Ix = oI; }
        }
        if (part == 0) {
            tok_next[row] = Ix;
            lse_out[t * B + row] = M + logf(S);
        }
    }
}

// final pass: out[b][t][v] -= lse[t][b]   (tier A)
__global__ __launch_bounds__(256) void sublse_kernel(
    float* __restrict__ out, const float* __restrict__ lse)
{
    const size_t n4 = BTV / 4;
    size_t i4 = (size_t)blockIdx.x * 256 + threadIdx.x;
    const size_t stride = (size_t)gridDim.x * 256;
    for (; i4 < n4; i4 += stride) {
        size_t b = i4 / (TV / 4);
        size_t t = (i4 % (TV / 4)) / (V / 4);
        float l = lse[t * B + b];
        float4 v = *(float4*)(out + i4 * 4);
        v.x -= l; v.y -= l; v.z -= l; v.w -= l;
        *(float4*)(out + i4 * 4) = v;
    }
}

// ---------------- tier-B (fallback) kernels: unchanged from R0 ----------------

__global__ __launch_bounds__(256) void logits_kernel(
    const float* __restrict__ h1, const float* __restrict__ wout,
    const float* __restrict__ bout, float* __restrict__ out, int t,
    float* __restrict__ pm, float* __restrict__ ps, int* __restrict__ pidx)
{
    const int tid = threadIdx.x, blk = blockIdx.x;
    const int tx = tid & 7, ty = tid >> 3;
    __shared__ float4 As4[B][9];
    __shared__ float4 Ws4[128][9];
    float acc[4][4] = {};

    for (int kc = 0; kc < H; kc += 32) {
        {
            int row = tid >> 3, c = tid & 7;
            As4[row][c] = *(const float4*)(h1 + (size_t)row * H + kc + c * 4);
        }
        for (int u = tid; u < 128 * 8; u += 256) {
            int row = u >> 3, c = u & 7;
            Ws4[row][c] = *(const float4*)(wout + (size_t)(blk * 128 + row) * H + kc + c * 4);
        }
        __syncthreads();
        #pragma unroll
        for (int kq = 0; kq < 8; ++kq) {
            float4 a[4], w[4];
            #pragma unroll
            for (int i = 0; i < 4; ++i) a[i] = As4[4 * tx + i][kq];
            #pragma unroll
            for (int j = 0; j < 4; ++j) w[j] = Ws4[4 * ty + j][kq];
            #pragma unroll
            for (int i = 0; i < 4; ++i)
                #pragma unroll
                for (int j = 0; j < 4; ++j)
                    acc[i][j] += a[i].x*w[j].x + a[i].y*w[j].y + a[i].z*w[j].z + a[i].w*w[j].w;
        }
        __syncthreads();
    }

    const int vbase = blk * 128 + 4 * ty;
    #pragma unroll
    for (int j = 0; j < 4; ++j) {
        float bb = bout[vbase + j];
        #pragma unroll
        for (int i = 0; i < 4; ++i) {
            acc[i][j] += bb;
            out[(size_t)(4 * tx + i) * TV + (size_t)t * V + vbase + j] = acc[i][j];
        }
    }

    __shared__ float rm[8][32];
    __shared__ int   ri[8][32];
    __shared__ float rs[8][32];
    __shared__ float Mrow[8];
    __shared__ int   Irow[8];
    for (int i = 0; i < 4; ++i) {
        int r = 4 * tx + i;
        float m = acc[i][0]; int mi = 0;
        #pragma unroll
        for (int j = 1; j < 4; ++j) if (acc[i][j] > m) { m = acc[i][j]; mi = j; }
        rm[tx][ty] = m; ri[tx][ty] = vbase + mi;
        __syncthreads();
        if (ty == 0) {
            float M = rm[tx][0]; int I = ri[tx][0];
            for (int u = 1; u < 32; ++u)
                if (rm[tx][u] > M) { M = rm[tx][u]; I = ri[tx][u]; }
            Mrow[tx] = M; Irow[tx] = I;
        }
        __syncthreads();
        float M = Mrow[tx];
        float s = 0.f;
        #pragma unroll
        for (int j = 0; j < 4; ++j) s += expf(acc[i][j] - M);
        rs[tx][ty] = s;
        __syncthreads();
        if (ty == 0) {
            float S = 0.f;
            for (int u = 0; u < 32; ++u) S += rs[tx][u];
            pm[(size_t)r * NVB + blk] = M;
            ps[(size_t)r * NVB + blk] = S;
            pidx[(size_t)r * NVB + blk] = Irow[tx];
        }
        __syncthreads();
    }
}

__global__ __launch_bounds__(256) void finalize_kernel(
    float* __restrict__ out, int t,
    const float* __restrict__ pm, const float* __restrict__ ps,
    const int* __restrict__ pidx, int* __restrict__ tok_next)
{
    const int row = blockIdx.y, chunk = blockIdx.x, tid = threadIdx.x;
    __shared__ float sm[256];
    __shared__ float ss[256];
    __shared__ int   si[256];
    float m = -INFINITY, s = 0.f; int ix = 0x7fffffff;
    if (tid < NVB) {
        m  = pm[(size_t)row * NVB + tid];
        s  = ps[(size_t)row * NVB + tid];
        ix = pidx[(size_t)row * NVB + tid];
    }
    sm[tid] = m; ss[tid] = s; si[tid] = ix;
    __syncthreads();
    for (int off = 128; off > 0; off >>= 1) {
        if (tid < off) {
            float ma = sm[tid], mb = sm[tid + off];
            float sa = ss[tid], sb = ss[tid + off];
            int   ia = si[tid], ib = si[tid + off];
            if (mb > ma || (mb == ma && ib < ia)) si[tid] = ib;
            float M, S;
            if (mb == -INFINITY)      { M = ma; S = sa; }
            else if (ma == -INFINITY) { M = mb; S = sb; }
            else {
                M = fmaxf(ma, mb);
                S = sa * expf(ma - M) + sb * expf(mb - M);
            }
            sm[tid] = M; ss[tid] = S;
        }
        __syncthreads();
    }
    __shared__ float slse;
    if (tid == 0) {
        slse = sm[0] + logf(ss[0]);
        if (chunk == 0) tok_next[row] = si[0];
    }
    __syncthreads();
    float lse = slse;
    size_t base = (size_t)row * TV + (size_t)t * V + (size_t)chunk * 1024;
    int lim = V - chunk * 1024; if (lim > 1024) lim = 1024;
    for (int i = tid; i < lim; i += 256) out[base + i] -= lse;
}

extern "C" void kernel_launch(void* const* d_in, const int* in_sizes, int n_in,
                              void* d_out, int out_size, void* d_ws, size_t ws_size,
                              hipStream_t stream)
{
    const float* enc_hid = (const float*)d_in[1];
    const float* emb     = (const float*)d_in[2];
    const float* w_ih0   = (const float*)d_in[3];
    const float* w_hh0   = (const float*)d_in[4];
    const float* b_ih0   = (const float*)d_in[5];
    const float* b_hh0   = (const float*)d_in[6];
    const float* w_ih1   = (const float*)d_in[7];
    const float* w_hh1   = (const float*)d_in[8];
    const float* b_ih1   = (const float*)d_in[9];
    const float* b_hh1   = (const float*)d_in[10];
    const float* w_out   = (const float*)d_in[11];
    const float* b_out   = (const float*)d_in[12];

    float* out = (float*)d_out;

    if (ws_size >= NEED_A) {
        // ---------------- tier A: MFMA logits ----------------
        __bf16* Whi = (__bf16*)d_ws;
        __bf16* Wlo = Whi + (size_t)V * H;
        float* wsf = (float*)d_ws + AF_BASE;
        float* H0   = wsf + AH0;
        float* H1   = wsf + AH1;
        float* GI0  = wsf + AGI0;
        float* GH0  = wsf + AGH0;
        float* GI1  = wsf + AGI1;
        float* GH1  = wsf + AGH1;
        __bf16* H1HI = (__bf16*)(wsf + AH1HI);
        __bf16* H1LO = (__bf16*)(wsf + AH1LO);
        float* PM   = wsf + APM;
        float* PS   = wsf + APS;
        int*   PI   = (int*)(wsf + API);
        int*   TOK  = (int*)(wsf + ATOK);
        float* LSE  = wsf + ALSE;
        int*   CNT  = (int*)(wsf + ACNT);

        init_kernel<<<256, 256, 0, stream>>>(enc_hid, H0, H1, TOK, CNT);
        splitw_kernel<<<2048, 256, 0, stream>>>(w_out, Whi, Wlo);

        for (int t = 0; t < T; ++t) {
            float* h0o = H0 + (t & 1) * (B * H);
            float* h0n = H0 + ((t + 1) & 1) * (B * H);
            float* h1o = H1 + (t & 1) * (B * H);
            float* h1n = H1 + ((t + 1) & 1) * (B * H);
            const int* tok_t = TOK + t * B;

            gates_kernel<<<192, 256, 0, stream>>>(nullptr, emb, tok_t, h0o,
                                                  w_ih0, E, w_hh0, GI0, GH0);
            gru_combine<<<128, 256, 0, stream>>>(GI0, GH0, b_ih0, b_hh0, h0o, h0n,
                                                 (t == T - 1) ? (out + BTV) : nullptr,
                                                 nullptr, nullptr);
            gates_kernel<<<192, 256, 0, stream>>>(h0n, nullptr, nullptr, h1o,
                                                  w_ih1, H, w_hh1, GI1, GH1);
            gru_combine<<<128, 256, 0, stream>>>(GI1, GH1, b_ih1, b_hh1, h1o, h1n,
                                                 (t == T - 1) ? (out + BTV + B * H) : nullptr,
                                                 H1HI, H1LO);
            logits_mfma_kernel<<<NVB, 256, 0, stream>>>(H1HI, H1LO, Whi, Wlo,
                                                        b_out, out, t, PM, PS, PI,
                                                        TOK + (t + 1) * B, LSE, CNT);
        }
        sublse_kernel<<<2048, 256, 0, stream>>>(out, LSE);
    } else {
        // ---------------- tier B: R0 fallback ----------------
        float* ws  = (float*)d_ws;
        float* H0  = ws + WS_H0;
        float* H1  = ws + WS_H1;
        float* GI0 = ws + WS_GI0;
        float* GH0 = ws + WS_GH0;
        float* GI1 = ws + WS_GI1;
        float* GH1 = ws + WS_GH1;
        float* PM  = ws + WS_PM;
        float* PS  = ws + WS_PS;
        int*   PI  = (int*)(ws + WS_PI);
        int*   TOK = (int*)(ws + WS_TOK);

        init_kernel<<<256, 256, 0, stream>>>(enc_hid, H0, H1, TOK, nullptr);

        for (int t = 0; t < T; ++t) {
            float* h0o = H0 + (t & 1) * (B * H);
            float* h0n = H0 + ((t + 1) & 1) * (B * H);
            float* h1o = H1 + (t & 1) * (B * H);
            float* h1n = H1 + ((t + 1) & 1) * (B * H);
            const int* tok_t = TOK + t * B;

            gates_kernel<<<192, 256, 0, stream>>>(nullptr, emb, tok_t, h0o,
                                                  w_ih0, E, w_hh0, GI0, GH0);
            gru_combine<<<128, 256, 0, stream>>>(GI0, GH0, b_ih0, b_hh0, h0o, h0n,
                                                 (t == T - 1) ? (out + BTV) : nullptr,
                                                 nullptr, nullptr);
            gates_kernel<<<192, 256, 0, stream>>>(h0n, nullptr, nullptr, h1o,
                                                  w_ih1, H, w_hh1, GI1, GH1);
            gru_combine<<<128, 256, 0, stream>>>(GI1, GH1, b_ih1, b_hh1, h1o, h1n,
                                                 (t == T - 1) ? (out + BTV + B * H) : nullptr,
                                                 nullptr, nullptr);
            logits_kernel<<<NVB, 256, 0, stream>>>(h1n, w_out, b_out, out, t, PM, PS, PI);
            finalize_kernel<<<dim3(32, 32), 256, 0, stream>>>(out, t, PM, PS, PI,
                                                              TOK + (t + 1) * B);
        }
    }
}

// Round 3
// 7055.129 us; speedup vs baseline: 2.0258x; 2.0258x over previous
//
#include <hip/hip_runtime.h>
#include <hip/hip_bf16.h>
#include <math.h>

// Problem constants
#define B   32
#define T   64
#define E   512
#define H   1024
#define V   32000
#define G3  3072            // 3*H
#define TV  (T*V)
#define BTV ((size_t)B*T*V)
#define SOS 1
#define NPC 1000            // logits partial columns (500 blocks * 2 waves)

// ws layout (float offsets) — total 526,112 floats = 2.01 MB (< R0's proven 2.2 MB)
#define WS_H0    0          // B*H f32 (single buffer, elementwise update)
#define WS_H1    32768
#define WS_GI0   65536      // B*3H f32   (GI1 aliases this — GI0 consumed before GI1 written)
#define WS_GH0   163840
#define WS_GH1   262144
#define WS_H0HI  360448     // B*H bf16 = 16384 f32 slots
#define WS_H0LO  376832
#define WS_H1HI  393216
#define WS_H1LO  409600
#define WS_PM    425984     // B*NPC f32
#define WS_PS    457984
#define WS_PI    489984     // B*NPC int
#define WS_TOK   521984     // (T+1)*B int
#define WS_LSE   524064     // T*B f32
// end 526112

typedef __bf16 bf8   __attribute__((ext_vector_type(8)));
typedef float  f32x4 __attribute__((ext_vector_type(4)));

__device__ inline f32x4 mfma16(bf8 a, bf8 b, f32x4 c) {
    return __builtin_amdgcn_mfma_f32_16x16x32_bf16(a, b, c, 0, 0, 0);
}

// split 8 consecutive f32 into hi/lo bf16 fragments (RNE hi, residual lo)
__device__ inline void split8(const float* __restrict__ p, bf8& hi, bf8& lo) {
    float4 u = *(const float4*)p;
    float4 v = *(const float4*)(p + 4);
    float f[8] = {u.x, u.y, u.z, u.w, v.x, v.y, v.z, v.w};
    #pragma unroll
    for (int i = 0; i < 8; ++i) {
        __bf16 h = (__bf16)f[i];
        hi[i] = h;
        lo[i] = (__bf16)(f[i] - (float)h);
    }
}

// One wave computes C[0:32, cols:cols+32] = A[32,K] @ W[N,K]^T (3-term split-bf16).
// MODE 0: A pre-split bf16 hi/lo (stride K). MODE 1: A = emb[tok[m]] f32, split in-reg.
template<int MODE>
__device__ inline void mm_tile(
    const __bf16* __restrict__ Ahi, const __bf16* __restrict__ Alo,
    const float* __restrict__ emb, const int* __restrict__ tok,
    const float* __restrict__ W, int K, int cols, int lane,
    f32x4& a00, f32x4& a01, f32x4& a10, f32x4& a11)
{
    const int q = lane >> 4, r = lane & 15, koff = q * 8;
    const float* w0 = W + (size_t)(cols + r) * K + koff;
    const float* w1 = w0 + (size_t)16 * K;
    const __bf16 *p0h = nullptr, *p0l = nullptr, *p1h = nullptr, *p1l = nullptr;
    const float *e0 = nullptr, *e1 = nullptr;
    if (MODE == 0) {
        p0h = Ahi + r * K + koff;  p0l = Alo + r * K + koff;
        p1h = p0h + 16 * K;        p1l = p0l + 16 * K;
    } else {
        e0 = emb + (size_t)tok[r] * K + koff;
        e1 = emb + (size_t)tok[r + 16] * K + koff;
    }
    #pragma unroll 2
    for (int ko = 0; ko < K; ko += 32) {
        bf8 A0h, A0l, A1h, A1l, W0h, W0l, W1h, W1l;
        if (MODE == 0) {
            A0h = *(const bf8*)(p0h + ko);  A0l = *(const bf8*)(p0l + ko);
            A1h = *(const bf8*)(p1h + ko);  A1l = *(const bf8*)(p1l + ko);
        } else {
            split8(e0 + ko, A0h, A0l);
            split8(e1 + ko, A1h, A1l);
        }
        split8(w0 + ko, W0h, W0l);
        split8(w1 + ko, W1h, W1l);
        a00 = mfma16(A0l, W0h, a00); a00 = mfma16(A0h, W0l, a00); a00 = mfma16(A0h, W0h, a00);
        a01 = mfma16(A0l, W1h, a01); a01 = mfma16(A0h, W1l, a01); a01 = mfma16(A0h, W1h, a01);
        a10 = mfma16(A1l, W0h, a10); a10 = mfma16(A1h, W0l, a10); a10 = mfma16(A1h, W0h, a10);
        a11 = mfma16(A1l, W1h, a11); a11 = mfma16(A1h, W1l, a11); a11 = mfma16(A1h, W1h, a11);
    }
}

__global__ __launch_bounds__(256) void init2(
    const float* __restrict__ ehid, float* __restrict__ h0, float* __restrict__ h1,
    __bf16* __restrict__ h0hi, __bf16* __restrict__ h0lo,
    __bf16* __restrict__ h1hi, __bf16* __restrict__ h1lo, int* __restrict__ tok0)
{
    int idx = blockIdx.x * 256 + threadIdx.x;   // 0..65535
    float v = ehid[idx];
    __bf16 hb = (__bf16)v;
    __bf16 lb = (__bf16)(v - (float)hb);
    if (idx < B * H) { h0[idx] = v; h0hi[idx] = hb; h0lo[idx] = lb; }
    else { int j = idx - B * H; h1[j] = v; h1hi[j] = hb; h1lo[j] = lb; }
    if (idx < B) tok0[idx] = SOS;
}

// K1: 144 blocks x 128 thr: [0,48) Gh0 = h0 @ w_hh0^T; [48,96) Gh1 = h1 @ w_hh1^T;
// [96,144) Gi0 = emb[tok] @ w_ih0^T (K=512)
__global__ __launch_bounds__(128) void gates_mfma(
    const __bf16* __restrict__ h0hi, const __bf16* __restrict__ h0lo,
    const __bf16* __restrict__ h1hi, const __bf16* __restrict__ h1lo,
    const float* __restrict__ emb, const int* __restrict__ tok,
    const float* __restrict__ whh0, const float* __restrict__ whh1,
    const float* __restrict__ wih0,
    float* __restrict__ GH0, float* __restrict__ GH1, float* __restrict__ GI0)
{
    const int blk = blockIdx.x, tid = threadIdx.x;
    const int wave = tid >> 6, lane = tid & 63;
    const int seg = blk / 48, sub = blk % 48;
    const int cols = sub * 64 + wave * 32;
    f32x4 a00 = {0.f,0.f,0.f,0.f}, a01 = {0.f,0.f,0.f,0.f};
    f32x4 a10 = {0.f,0.f,0.f,0.f}, a11 = {0.f,0.f,0.f,0.f};
    float* C;
    if (seg == 0)      { mm_tile<0>(h0hi, h0lo, nullptr, nullptr, whh0, H, cols, lane, a00,a01,a10,a11); C = GH0; }
    else if (seg == 1) { mm_tile<0>(h1hi, h1lo, nullptr, nullptr, whh1, H, cols, lane, a00,a01,a10,a11); C = GH1; }
    else               { mm_tile<1>(nullptr, nullptr, emb, tok, wih0, E, cols, lane, a00,a01,a10,a11); C = GI0; }
    const int q = lane >> 4, r = lane & 15;
    #pragma unroll
    for (int reg = 0; reg < 4; ++reg) {
        int m0 = q * 4 + reg, m1 = m0 + 16;
        C[(size_t)m0 * G3 + cols + r]      = a00[reg];
        C[(size_t)m0 * G3 + cols + 16 + r] = a01[reg];
        C[(size_t)m1 * G3 + cols + r]      = a10[reg];
        C[(size_t)m1 * G3 + cols + 16 + r] = a11[reg];
    }
}

// K3: 48 blocks: Gi1 = h0new @ w_ih1^T
__global__ __launch_bounds__(128) void gi1_mfma(
    const __bf16* __restrict__ h0hi, const __bf16* __restrict__ h0lo,
    const float* __restrict__ wih1, float* __restrict__ GI1)
{
    const int blk = blockIdx.x, tid = threadIdx.x;
    const int wave = tid >> 6, lane = tid & 63;
    const int cols = blk * 64 + wave * 32;
    f32x4 a00 = {0.f,0.f,0.f,0.f}, a01 = {0.f,0.f,0.f,0.f};
    f32x4 a10 = {0.f,0.f,0.f,0.f}, a11 = {0.f,0.f,0.f,0.f};
    mm_tile<0>(h0hi, h0lo, nullptr, nullptr, wih1, H, cols, lane, a00,a01,a10,a11);
    const int q = lane >> 4, r = lane & 15;
    #pragma unroll
    for (int reg = 0; reg < 4; ++reg) {
        int m0 = q * 4 + reg, m1 = m0 + 16;
        GI1[(size_t)m0 * G3 + cols + r]      = a00[reg];
        GI1[(size_t)m0 * G3 + cols + 16 + r] = a01[reg];
        GI1[(size_t)m1 * G3 + cols + r]      = a10[reg];
        GI1[(size_t)m1 * G3 + cols + 16 + r] = a11[reg];
    }
}

// PyTorch GRU cell combine (gates r,z,n at cols j, j+H, j+2H); single-buffer h update;
// emits bf16 hi/lo split of the new h for downstream MFMA consumers.
__global__ __launch_bounds__(256) void gru_combine2(
    const float* __restrict__ Gi, const float* __restrict__ Gh,
    const float* __restrict__ bih, const float* __restrict__ bhh,
    float* __restrict__ h, __bf16* __restrict__ hhi, __bf16* __restrict__ hlo,
    float* __restrict__ fin)
{
    int idx = blockIdx.x * 256 + threadIdx.x;   // 0..32767
    int b = idx >> 10, j = idx & 1023;
    size_t g = (size_t)b * G3 + j;
    float ir  = Gi[g]         + bih[j];
    float hr  = Gh[g]         + bhh[j];
    float iz  = Gi[g + H]     + bih[j + H];
    float hz  = Gh[g + H]     + bhh[j + H];
    float in_ = Gi[g + 2*H]   + bih[j + 2*H];
    float hn  = Gh[g + 2*H]   + bhh[j + 2*H];
    float r = 1.f / (1.f + expf(-(ir + hr)));
    float z = 1.f / (1.f + expf(-(iz + hz)));
    float n = tanhf(in_ + r * hn);
    float hv = (1.f - z) * n + z * h[idx];
    h[idx] = hv;
    __bf16 hb = (__bf16)hv;
    hhi[idx] = hb;
    hlo[idx] = (__bf16)(hv - (float)hb);
    if (fin) fin[idx] = hv;
}

// per-(row) partial over this wave's 32 cols: max/argmax(first-occurrence)/sumexp
__device__ inline void row_partial(float v0, float v1, int cols, int r, int row,
    int pcol, float* __restrict__ pm, float* __restrict__ ps, int* __restrict__ pidx)
{
    float mx; int ix;
    if (v1 > v0) { mx = v1; ix = cols + 16 + r; }
    else         { mx = v0; ix = cols + r; }
    #pragma unroll
    for (int mask = 8; mask; mask >>= 1) {
        float om = __shfl_xor(mx, mask, 16);
        int   oi = __shfl_xor(ix, mask, 16);
        if (om > mx || (om == mx && oi < ix)) { mx = om; ix = oi; }
    }
    float s = expf(v0 - mx) + expf(v1 - mx);
    #pragma unroll
    for (int mask = 8; mask; mask >>= 1) s += __shfl_xor(s, mask, 16);
    if (r == 0) {
        pm[(size_t)row * NPC + pcol] = mx;
        ps[(size_t)row * NPC + pcol] = s;
        pidx[(size_t)row * NPC + pcol] = ix;
    }
}

// K5: 500 blocks x 128 thr: logits tile 32 b x 64 v, on-the-fly W split, raw logits -> out
__global__ __launch_bounds__(128) void logits_mfma2(
    const __bf16* __restrict__ h1hi, const __bf16* __restrict__ h1lo,
    const float* __restrict__ wout, const float* __restrict__ bout,
    float* __restrict__ out, int t,
    float* __restrict__ pm, float* __restrict__ ps, int* __restrict__ pidx)
{
    const int blk = blockIdx.x, tid = threadIdx.x;
    const int wave = tid >> 6, lane = tid & 63;
    const int cols = blk * 64 + wave * 32;
    f32x4 a00 = {0.f,0.f,0.f,0.f}, a01 = {0.f,0.f,0.f,0.f};
    f32x4 a10 = {0.f,0.f,0.f,0.f}, a11 = {0.f,0.f,0.f,0.f};
    mm_tile<0>(h1hi, h1lo, nullptr, nullptr, wout, H, cols, lane, a00,a01,a10,a11);
    const int q = lane >> 4, r = lane & 15;
    const float bb0 = bout[cols + r], bb1 = bout[cols + 16 + r];
    const int pcol = blk * 2 + wave;
    const size_t ob = (size_t)t * V + cols + r;
    #pragma unroll
    for (int reg = 0; reg < 4; ++reg) {
        int m0 = q * 4 + reg;
        float v00 = a00[reg] + bb0, v01 = a01[reg] + bb1;
        out[(size_t)m0 * TV + ob]      = v00;
        out[(size_t)m0 * TV + ob + 16] = v01;
        row_partial(v00, v01, cols, r, m0, pcol, pm, ps, pidx);
        int m1 = m0 + 16;
        float v10 = a10[reg] + bb0, v11 = a11[reg] + bb1;
        out[(size_t)m1 * TV + ob]      = v10;
        out[(size_t)m1 * TV + ob + 16] = v11;
        row_partial(v10, v11, cols, r, m1, pcol, pm, ps, pidx);
    }
}

// K6: 32 blocks (one per batch row): merge 1000 partials -> next token + LSE[t]
__global__ __launch_bounds__(256) void finalize2(
    const float* __restrict__ pm, const float* __restrict__ ps,
    const int* __restrict__ pidx, int* __restrict__ tok_next,
    float* __restrict__ lse, int t)
{
    const int row = blockIdx.x, tid = threadIdx.x;
    const float* pmr = pm + (size_t)row * NPC;
    const float* psr = ps + (size_t)row * NPC;
    const int*   pir = pidx + (size_t)row * NPC;
    float M = -INFINITY, S = 0.f; int I = 0x7fffffff;
    for (int c = tid; c < NPC; c += 256) {          // increasing c: first-occurrence ties
        float m = pmr[c], s = psr[c]; int i = pir[c];
        if (m > M) { S = S * expf(M - m) + s; M = m; I = i; }
        else { S += s * expf(m - M); if (m == M && i < I) I = i; }
    }
    __shared__ float sm[256], ss[256];
    __shared__ int   si[256];
    sm[tid] = M; ss[tid] = S; si[tid] = I;
    __syncthreads();
    for (int off = 128; off; off >>= 1) {
        if (tid < off) {
            float ma = sm[tid], sa = ss[tid]; int ia = si[tid];
            float mb = sm[tid + off], sb = ss[tid + off]; int ib = si[tid + off];
            float MM = fmaxf(ma, mb);
            float SS = sa * expf(ma - MM) + sb * expf(mb - MM);
            si[tid] = (mb > ma || (mb == ma && ib < ia)) ? ib : ia;
            sm[tid] = MM; ss[tid] = SS;
        }
        __syncthreads();
    }
    if (tid == 0) {
        tok_next[row] = si[0];
        lse[t * B + row] = sm[0] + logf(ss[0]);
    }
}

// end: out[b][t][v] -= lse[t][b]
__global__ __launch_bounds__(256) void sublse_kernel(
    float* __restrict__ out, const float* __restrict__ lse)
{
    const size_t n4 = BTV / 4;
    size_t i4 = (size_t)blockIdx.x * 256 + threadIdx.x;
    const size_t stride = (size_t)gridDim.x * 256;
    for (; i4 < n4; i4 += stride) {
        size_t b = i4 / (TV / 4);
        size_t t = (i4 % (TV / 4)) / (V / 4);
        float l = lse[t * B + b];
        float4 v = *(float4*)(out + i4 * 4);
        v.x -= l; v.y -= l; v.z -= l; v.w -= l;
        *(float4*)(out + i4 * 4) = v;
    }
}

extern "C" void kernel_launch(void* const* d_in, const int* in_sizes, int n_in,
                              void* d_out, int out_size, void* d_ws, size_t ws_size,
                              hipStream_t stream)
{
    const float* enc_hid = (const float*)d_in[1];
    const float* emb     = (const float*)d_in[2];
    const float* w_ih0   = (const float*)d_in[3];
    const float* w_hh0   = (const float*)d_in[4];
    const float* b_ih0   = (const float*)d_in[5];
    const float* b_hh0   = (const float*)d_in[6];
    const float* w_ih1   = (const float*)d_in[7];
    const float* w_hh1   = (const float*)d_in[8];
    const float* b_ih1   = (const float*)d_in[9];
    const float* b_hh1   = (const float*)d_in[10];
    const float* w_out   = (const float*)d_in[11];
    const float* b_out   = (const float*)d_in[12];

    float* out = (float*)d_out;
    float* ws  = (float*)d_ws;

    float*  H0   = ws + WS_H0;
    float*  H1   = ws + WS_H1;
    float*  GI0  = ws + WS_GI0;       // GI1 aliases GI0 (GI0 consumed before GI1 written)
    float*  GH0  = ws + WS_GH0;
    float*  GH1  = ws + WS_GH1;
    float*  GI1  = GI0;
    __bf16* H0HI = (__bf16*)(ws + WS_H0HI);
    __bf16* H0LO = (__bf16*)(ws + WS_H0LO);
    __bf16* H1HI = (__bf16*)(ws + WS_H1HI);
    __bf16* H1LO = (__bf16*)(ws + WS_H1LO);
    float*  PM   = ws + WS_PM;
    float*  PS   = ws + WS_PS;
    int*    PI   = (int*)(ws + WS_PI);
    int*    TOK  = (int*)(ws + WS_TOK);
    float*  LSE  = ws + WS_LSE;

    init2<<<256, 256, 0, stream>>>(enc_hid, H0, H1, H0HI, H0LO, H1HI, H1LO, TOK);

    for (int t = 0; t < T; ++t) {
        const int* tok_t = TOK + t * B;
        // K1: Gh0 (h0_{t-1}), Gh1 (h1_{t-1}), Gi0 (emb[tok])
        gates_mfma<<<144, 128, 0, stream>>>(H0HI, H0LO, H1HI, H1LO, emb, tok_t,
                                            w_hh0, w_hh1, w_ih0, GH0, GH1, GI0);
        // K2: combine layer 0 -> h0 new (+ splits; h_fin at t=63)
        gru_combine2<<<128, 256, 0, stream>>>(GI0, GH0, b_ih0, b_hh0, H0, H0HI, H0LO,
                                              (t == T - 1) ? (out + BTV) : nullptr);
        // K3: Gi1 = h0new @ w_ih1^T (writes GI1 == GI0 buffer, after K2 consumed it)
        gi1_mfma<<<48, 128, 0, stream>>>(H0HI, H0LO, w_ih1, GI1);
        // K4: combine layer 1 -> h1 new (+ splits)
        gru_combine2<<<128, 256, 0, stream>>>(GI1, GH1, b_ih1, b_hh1, H1, H1HI, H1LO,
                                              (t == T - 1) ? (out + BTV + B * H) : nullptr);
        // K5: logits (raw) + per-wave partials
        logits_mfma2<<<500, 128, 0, stream>>>(H1HI, H1LO, w_out, b_out, out, t, PM, PS, PI);
        // K6: merge partials -> next token + LSE
        finalize2<<<32, 256, 0, stream>>>(PM, PS, PI, TOK + (t + 1) * B, LSE, t);
    }
    // log_softmax: subtract LSE over the whole output
    sublse_kernel<<<2048, 256, 0, stream>>>(out, LSE);
}